// Round 3
// 190.651 us; speedup vs baseline: 1.0002x; 1.0002x over previous
//
#include <hip/hip_runtime.h>

// GAE reverse scan: adv[t] = delta[t] + (gamma*lambda)*adv[t+1]
// delta[t] = reward[t] + gamma*value[t+1] - value[t]
//
// 2-pass sum-first + recompute structure (R1, compile-fixed R2, resubmitted R3
// after infra failure):
//   K1 gae_sum : per-(chunk, col4) weighted chunk sum only
//                  S_c = sum_k COEF^k * delta[16c+k]        (reads 131 MB, writes 4 MB)
//   K2 gae_out : carry_c = sum_{j>c} CL^(j-c-1) S_j  (S is L2-hot, <=63 f4 loads)
//                then local scan seeded with carry, write out ONCE (nontemporal).
// Rationale (R1 theory): old K1 wrote A_loc to out (68 MB) and old K3 read it
// back (67 MB) + rewrote (63 MB). Working set (131 MB in + 64 MB out + 4 MB S)
// fits the 256 MB Infinity Cache, so recomputing delta from L3-hot value/reward
// in pass 2 is far cheaper than the out RMW round-trip. Carry scan folded into
// pass 2 (each block computes its own suffix-weighted carry from S).
//
// R2 fix: __builtin_nontemporal_store requires a NATIVE vector type —
// HIP's float4 is a class (HIP_vector_type) and is rejected. Use
// ext_vector_type(4), same 16-byte layout.

constexpr int T_ = 1024;
constexpr int B_ = 16384;
constexpr int L_ = 16;        // chunk length
constexpr int C_ = T_ / L_;   // 64 chunks
constexpr float GAMMA = 0.99f;
constexpr float COEF  = (float)(0.99 * 0.97);

__host__ __device__ constexpr float pow_coef(int n) {
    float p = 1.0f;
    for (int i = 0; i < n; ++i) p *= COEF;
    return p;
}
constexpr float CL = pow_coef(L_);   // COEF^L

typedef float f32x4 __attribute__((ext_vector_type(4)));

static __device__ __forceinline__ void store_nt(float* p, float4 v) {
    f32x4 nv = {v.x, v.y, v.z, v.w};
    __builtin_nontemporal_store(nv, (f32x4*)p);
}

// ---------------- K1: weighted chunk sums only ----------------
__global__ __launch_bounds__(256) void gae_sum(
    const float* __restrict__ value,   // (T+1, B)
    const float* __restrict__ reward,  // (T, B)
    float* __restrict__ S)             // (C, B)
{
    const int c4    = blockIdx.x * 256 + threadIdx.x;
    const int chunk = blockIdx.y;
    const size_t b  = (size_t)c4 * 4;
    const int t0    = chunk * L_;

    // Batch ALL loads first: 17 value rows + 16 reward rows in flight.
    float4 v[L_ + 1];
    float4 r[L_];
    #pragma unroll
    for (int i = 0; i <= L_; ++i)
        v[i] = *(const float4*)(value + (size_t)(t0 + i) * B_ + b);
    #pragma unroll
    for (int i = 0; i < L_; ++i)
        r[i] = *(const float4*)(reward + (size_t)(t0 + i) * B_ + b);

    float4 s = make_float4(0.f, 0.f, 0.f, 0.f);
    #pragma unroll
    for (int i = L_ - 1; i >= 0; --i) {
        s.x = (r[i].x + GAMMA * v[i + 1].x - v[i].x) + COEF * s.x;
        s.y = (r[i].y + GAMMA * v[i + 1].y - v[i].y) + COEF * s.y;
        s.z = (r[i].z + GAMMA * v[i + 1].z - v[i].z) + COEF * s.z;
        s.w = (r[i].w + GAMMA * v[i + 1].w - v[i].w) + COEF * s.w;
    }
    *(float4*)(S + (size_t)chunk * B_ + b) = s;   // 4 MB total
}

// ---------------- K2: inline carry + recompute local scan + write out -------
__global__ __launch_bounds__(256) void gae_out(
    const float* __restrict__ value,   // (T+1, B)  L3-hot from K1
    const float* __restrict__ reward,  // (T, B)    L3-hot from K1
    const float* __restrict__ S,       // (C, B)    L2-hot, reused 64x
    float* __restrict__ out)           // (T, B)    written once, nontemporal
{
    const int c4    = blockIdx.x * 256 + threadIdx.x;
    const int chunk = blockIdx.y;
    const size_t b  = (size_t)c4 * 4;
    const int t0    = chunk * L_;

    // Issue the big input batch first so loads are in flight while the
    // carry chain (L2-hit latency) resolves.
    float4 v[L_ + 1];
    float4 r[L_];
    #pragma unroll
    for (int i = 0; i <= L_; ++i)
        v[i] = *(const float4*)(value + (size_t)(t0 + i) * B_ + b);
    #pragma unroll
    for (int i = 0; i < L_; ++i)
        r[i] = *(const float4*)(reward + (size_t)(t0 + i) * B_ + b);

    // carry entering chunk = sum_{j>chunk} CL^(j-chunk-1) * S_j, rolled in
    // reverse. chunk is wave-uniform (blockIdx.y) -> scalar loop, no divergence.
    float4 a = make_float4(0.f, 0.f, 0.f, 0.f);
    for (int j = C_ - 1; j > chunk; --j) {
        float4 s = *(const float4*)(S + (size_t)j * B_ + b);
        a.x = s.x + CL * a.x;
        a.y = s.y + CL * a.y;
        a.z = s.z + CL * a.z;
        a.w = s.w + CL * a.w;
    }

    // Local scan seeded with the carry; write out exactly once.
    #pragma unroll
    for (int i = L_ - 1; i >= 0; --i) {
        a.x = (r[i].x + GAMMA * v[i + 1].x - v[i].x) + COEF * a.x;
        a.y = (r[i].y + GAMMA * v[i + 1].y - v[i].y) + COEF * a.y;
        a.z = (r[i].z + GAMMA * v[i + 1].z - v[i].z) + COEF * a.z;
        a.w = (r[i].w + GAMMA * v[i + 1].w - v[i].w) + COEF * a.w;
        store_nt(out + (size_t)(t0 + i) * B_ + b, a);
    }
}

extern "C" void kernel_launch(void* const* d_in, const int* in_sizes, int n_in,
                              void* d_out, int out_size, void* d_ws, size_t ws_size,
                              hipStream_t stream) {
    const float* value  = (const float*)d_in[0];   // (T+1, B)
    const float* reward = (const float*)d_in[1];   // (T, B)
    float* out = (float*)d_out;
    float* S   = (float*)d_ws;                     // C*B*4 = 4 MiB

    dim3 block(256);
    dim3 grid(B_ / 4 / 256, C_);        // (16, 64)

    gae_sum<<<grid, block, 0, stream>>>(value, reward, S);
    gae_out<<<grid, block, 0, stream>>>(value, reward, S, out);
}